// Round 7
// baseline (1525.008 us; speedup 1.0000x reference)
//
#include <hip/hip_runtime.h>
#include <math.h>

typedef __attribute__((ext_vector_type(8))) short s8v;
typedef __attribute__((ext_vector_type(8))) _Float16 h8v;
typedef __attribute__((ext_vector_type(4))) float f4v;
typedef __attribute__((ext_vector_type(2))) int i2v;
typedef long long ll64;

#define L2E 1.44269504089f
#define INV2048 4.8828125e-4f
__device__ __forceinline__ float fexp2(float x) { return __builtin_amdgcn_exp2f(x); }
__device__ __forceinline__ float frcp(float x)  { return __builtin_amdgcn_rcpf(x); }
__device__ __forceinline__ float fsigm(float x) { return frcp(1.0f + fexp2(-L2E * x)); }
__device__ __forceinline__ float ftanh_(float x){ return 1.0f - 2.0f * frcp(fexp2((2.0f*L2E) * x) + 1.0f); }
__device__ __forceinline__ float rdl(float v, int l) {
    return __uint_as_float(__builtin_amdgcn_readlane(__float_as_uint(v), l));
}
__device__ __forceinline__ float bpermf(int byteidx, float v) {
    return __uint_as_float(__builtin_amdgcn_ds_bpermute(byteidx, __float_as_uint(v)));
}
#define WFENCE() asm volatile("s_waitcnt lgkmcnt(0)" ::: "memory")

// fp16 scaled split: x ~= hi + lo/2048, lo kept in normal fp16 range (flush-proof).
__device__ __forceinline__ void hsplit(float x, unsigned short& hi, unsigned short& lo) {
    _Float16 h = (_Float16)x;
    _Float16 l = (_Float16)((x - (float)h) * 2048.0f);
    hi = __builtin_bit_cast(unsigned short, h);
    lo = __builtin_bit_cast(unsigned short, l);
}
__device__ __forceinline__ float hjoin(unsigned short hi, unsigned short lo) {
    return (float)__builtin_bit_cast(_Float16, hi)
         + (float)__builtin_bit_cast(_Float16, lo) * INV2048;
}
__device__ __forceinline__ f4v mfmah(s8v a, s8v b, f4v c) {
    return __builtin_amdgcn_mfma_f32_16x16x32_f16(
        __builtin_bit_cast(h8v, a), __builtin_bit_cast(h8v, b), c, 0, 0, 0);
}
__device__ __forceinline__ f4v mfma8(ll64 a, ll64 b, f4v c) {
    return __builtin_amdgcn_mfma_f32_16x16x32_fp8_fp8(a, b, c, 0, 0, 0);
}
// fp16x8 fragment -> fp8(e4m3)x8 operand (same k ordering: byte j = elem j)
__device__ __forceinline__ ll64 pk8(s8v hf) {
    h8v h = __builtin_bit_cast(h8v, hf);
    int lo = __builtin_amdgcn_cvt_pk_fp8_f32((float)h[0], (float)h[1], 0, false);
    lo = __builtin_amdgcn_cvt_pk_fp8_f32((float)h[2], (float)h[3], lo, true);
    int hi = __builtin_amdgcn_cvt_pk_fp8_f32((float)h[4], (float)h[5], 0, false);
    hi = __builtin_amdgcn_cvt_pk_fp8_f32((float)h[6], (float)h[7], hi, true);
    i2v r; r[0] = lo; r[1] = hi;
    return __builtin_bit_cast(ll64, r);
}
__device__ __forceinline__ unsigned char fp8b(float x) {
    return (unsigned char)(__builtin_amdgcn_cvt_pk_fp8_f32(x, 0.0f, 0, false) & 0xff);
}

// ---------------- d_ws layout (global, unchanged) ----------------
// GHI  [0,      65536): gates hi fp16, frag f = nt*4+mat*2+kh (64 frags x 1024 B)
// GLO  [65536,  98304): gates lo fp8  (64 frags x 512 B)
// CHI  [98304, 114688): gcn hi fp16,  frag f = g*8+nt*2+kh (16 x 1024) -> REGISTERS (pinned)
// CLO  [114688,122880): gcn lo fp8    (16 x 512)                      -> REGISTERS (pinned)
// DHI  [122880,126976): dec hi fp16,  frag f = nt*2+kh (4 x 1024)     -> REGISTERS (pinned)
#define OFF_GLO  65536
#define OFF_CHI  98304
#define OFF_CLO  114688
#define OFF_DHI  122880

// ---------------- LDS layout (bytes), total 163328 ----------------
// GHI  [0,      65536): gates hi fp16
// GLO  [65536,  98304): gates lo fp8
// ACTS [98304, 159744): 8 waves x 7680 B (3840 shorts):
//   SHI@0 SLO@960 HHI@1920 HLO@2880 (15 rows x 64 shorts, XOR-swizzled)
// ENCW [159744,162560): enc_w fp32 (704 floats)
// D2W  [162560,163328): dec_w2 fp32 (192 floats)
// Row packing: batch0 -> MFMA rows 0..6, batch1 -> rows 8..14.
// Swizzle: short-index col' = col ^ ((row&7)<<3).
#define L_GLO   65536
#define L_ACT   98304
#define L_ENCW  159744
#define L_D2W   162560

// ---------- prologue: build ALL weight fragments into d_ws (unchanged) ----------
__global__ __launch_bounds__(256) void build_ws(
    const float* __restrict__ g1w, const float* __restrict__ g2w,
    const float* __restrict__ d1w, const float* __restrict__ wih,
    const float* __restrict__ whh, unsigned char* __restrict__ ws)
{
    const int tid = threadIdx.x;  // 256
    unsigned short* GHI = (unsigned short*)ws;
    unsigned char*  GLO = ws + OFF_GLO;
    unsigned short* CHI = (unsigned short*)(ws + OFF_CHI);
    unsigned char*  CLO = ws + OFF_CLO;
    unsigned short* DHI = (unsigned short*)(ws + OFF_DHI);

    // gates: B[k][c] = wih/whh[c*64+k]
    for (int u = tid; u < 4096; u += 256) {
        int f = u >> 6, ln = u & 63;
        int nt = f >> 2, mat = (f >> 1) & 1, kh = f & 1;
        int col = nt * 16 + (ln & 15);
        int k0 = kh * 32 + ((ln >> 4) & 3) * 8;
        const float* W = mat ? whh : wih;
        #pragma unroll
        for (int j = 0; j < 8; ++j) {
            float w = W[col * 64 + k0 + j];
            _Float16 h = (_Float16)w;
            float r = (w - (float)h) * 2048.0f;
            GHI[f * 512 + ln * 8 + j] = __builtin_bit_cast(unsigned short, h);
            GLO[f * 512 + ln * 8 + j] = fp8b(r);
        }
    }
    // gcn: B[k][n] = W[k*64+n]
    for (int u = tid; u < 1024; u += 256) {
        int f = u >> 6, ln = u & 63;
        int g = f >> 3, nt = (f >> 1) & 3, kh = f & 1;
        int n = nt * 16 + (ln & 15);
        int k0 = kh * 32 + ((ln >> 4) & 3) * 8;
        const float* W = g ? g2w : g1w;
        #pragma unroll
        for (int j = 0; j < 8; ++j) {
            float w = W[(k0 + j) * 64 + n];
            _Float16 h = (_Float16)w;
            float r = (w - (float)h) * 2048.0f;
            CHI[f * 512 + ln * 8 + j] = __builtin_bit_cast(unsigned short, h);
            CLO[f * 512 + ln * 8 + j] = fp8b(r);
        }
    }
    // dec: B[k][j] = d1w[k*32+j], hi only
    for (int u = tid; u < 256; u += 256) {
        int f = u >> 6, ln = u & 63;
        int nt = f >> 1, kh = f & 1;
        int n = nt * 16 + (ln & 15);
        int k0 = kh * 32 + ((ln >> 4) & 3) * 8;
        #pragma unroll
        for (int j = 0; j < 8; ++j) {
            _Float16 h = (_Float16)d1w[(k0 + j) * 32 + n];
            DHI[f * 512 + ln * 8 + j] = __builtin_bit_cast(unsigned short, h);
        }
    }
}

// ---------- main kernel: one wave = TWO batches (rows 0-6 / 8-14), one pass ----------
// Register-budget fix, take 3. Empirics: (512,2) -> VGPR cap 128 exactly =
// 512-reg file / 4 waves, i.e. hipcc treats arg2 as min BLOCKS/CU (CUDA
// semantics): 2 blocks x 8 waves / 4 SIMDs = 4 waves/SIMD. The 112 pinned
// weight VGPRs then spill to scratch -> ~2 GB/dispatch refill storm
// (FETCH ~= dur x 1.4 TB/s). amdgpu_waves_per_eu(2) was a no-op (R6 == R4).
// (512, 1) gives cap >= 256 under EITHER interpretation:
//   blocks/CU:  1 block/CU -> 2 waves/SIMD -> 256 VGPRs
//   waves/EU:   min 1 wave/EU -> 512 VGPRs
// LDS (163 KB) already limits to 1 block/CU, so this costs zero occupancy.
__global__ __launch_bounds__(512, 1)
void stgnn(const float* __restrict__ xh,   const float* __restrict__ adj,
           const float* __restrict__ encw, const float* __restrict__ encb,
           const float* __restrict__ g1b,  const float* __restrict__ g2b,
           const float* __restrict__ bih,  const float* __restrict__ bhh,
           const float* __restrict__ d1b,  const float* __restrict__ d2w,
           const float* __restrict__ d2b,  const unsigned char* __restrict__ ws,
           float* __restrict__ out)
{
    __shared__ __align__(16) unsigned char pool[163328];

    const int tid  = threadIdx.x;
    const int lane = tid & 63;
    const int wv   = tid >> 6;
    const int q    = lane >> 4;
    const int c15  = lane & 15;
    const int bat0 = blockIdx.x * 16 + wv * 2;
    const int bat1 = bat0 + 1;

    // ---- one-time: stage GHI+GLO (contiguous 98304 B) + encw/d2w into LDS ----
    {
        s8v* dst = (s8v*)pool;
        const s8v* src = (const s8v*)ws;
        for (int i = tid; i < 6144; i += 512) dst[i] = src[i];
        float* pe = (float*)(pool + L_ENCW);
        for (int i = tid; i < 704; i += 512) pe[i] = encw[i];
        float* pd = (float*)(pool + L_D2W);
        if (tid < 192) pd[tid] = d2w[tid];
    }

    // ---- per-lane registerized weight fragments (CHI/CLO), global read once ----
    // Pin via empty asm: asm outputs are non-rematerializable -> must stay in VGPRs.
    s8v  chiR[16];
    ll64 cloR[16];
    {
        const s8v*  CHIg = (const s8v*)(ws + OFF_CHI);
        const ll64* CLOg = (const ll64*)(ws + OFF_CLO);
        #pragma unroll
        for (int f = 0; f < 16; ++f) chiR[f] = CHIg[f * 64 + lane];
        #pragma unroll
        for (int f = 0; f < 16; ++f) cloR[f] = CLOg[f * 64 + lane];
        #pragma unroll
        for (int f = 0; f < 16; ++f) {
            asm volatile("" : "+v"(chiR[f]));
            asm volatile("" : "+v"(cloR[f]));
        }
    }

    unsigned short* aw = (unsigned short*)(pool + L_ACT) + wv * 3840;
    float* fw = (float*)aw;                       // float view of own act region
    const s8v* GHIv = (const s8v*)pool;
    const unsigned char* GLO = pool + L_GLO;
    const float* encwL = (const float*)(pool + L_ENCW);
    const float* d2wL  = (const float*)(pool + L_D2W);

    // ---- biases ----
    float benc = encb[lane];
    float bg1v[4], bg2v[4], bdec[2], biasg[16];
    #pragma unroll
    for (int i = 0; i < 4; ++i) { bg1v[i] = g1b[i * 16 + c15]; bg2v[i] = g2b[i * 16 + c15]; }
    #pragma unroll
    for (int i = 0; i < 2; ++i) bdec[i] = d1b[i * 16 + c15];
    #pragma unroll
    for (int i = 0; i < 16; ++i) biasg[i] = bih[i * 16 + c15] + bhh[i * 16 + c15];
    const int dn = lane / 6, dd = lane - dn * 6;    // dec2 mapping (lane<42)
    float bd2 = d2b[lane < 42 ? dd : 0];
    // lane-permutation constants for pred redistribution (replaces gapf LDS)
    const int l11  = lane - (lane / 11) * 11;       // lane % 11
    const bool up0 = (l11 < 6);                     // dynamic lanes in xr0
    const bool up1 = (lane >= 2) && (lane < 8);     // dynamic lanes in xr1
    const int fsrc = dn * 11 + dd;                  // old-pred source flat index
    const int osA  = fsrc * 4;                      // pull from xr0
    const int osB  = (fsrc >= 64 ? (fsrc - 64) : 0) * 4;  // pull from xr1 (dn==6)
    const bool selA = (dn < 6);
    const int bs0  = ((lane / 11) * 6 + l11) * 4;   // new-pred source for xr0 lanes
    const int bs1  = (34 + lane) * 4;               // new-pred source for xr1 lanes

    // ---- adjacency normalize for BOTH batches (wave-local float scratch) ----
    if (lane < 49) {
        int ai = lane / 7, aj = lane - ai * 7;
        float a0 = adj[(size_t)bat0 * 49 + lane];
        float a1 = adj[(size_t)bat1 * 49 + lane];
        if (ai == aj) { a0 = 1.0f; a1 = 1.0f; }
        fw[lane] = a0; fw[56 + lane] = a1;
    }
    WFENCE();
    float adjr0 = 0.0f, adjr1 = 0.0f;
    if (lane < 49) {
        int ai = lane / 7, aj = lane - ai * 7;
        float si0 = 0.f, sj0 = 0.f, si1 = 0.f, sj1 = 0.f;
        #pragma unroll
        for (int m = 0; m < 7; ++m) {
            si0 += fw[ai * 7 + m]; sj0 += fw[aj * 7 + m];
            si1 += fw[56 + ai * 7 + m]; sj1 += fw[56 + aj * 7 + m];
        }
        si0 = fmaxf(si0, 1.0f); sj0 = fmaxf(sj0, 1.0f);
        si1 = fmaxf(si1, 1.0f); sj1 = fmaxf(sj1, 1.0f);
        adjr0 = fw[lane] / (sqrtf(si0) * sqrtf(sj0));
        adjr1 = fw[56 + lane] / (sqrtf(si1) * sqrtf(sj1));
    }
    WFENCE();
    // zero hx buffers (HHI+HLO: shorts [1920,3840))
    #pragma unroll
    for (int i = 0; i < 30; ++i) aw[1920 + i * 64 + lane] = 0;
    WFENCE();
    __syncthreads();   // LDS staging complete

    float cx[16];
    #pragma unroll
    for (int i = 0; i < 16; ++i) cx[i] = 0.0f;
    float xr0 = 0.f, xr1 = 0.f, xr2 = 0.f, xr3 = 0.f;

    // swizzled fragment k-offsets (within-row): col' = col ^ ((row&7)<<3)
    const int swz = (c15 & 7) << 3;
    const int fo0 = (q * 8) ^ swz;          // k 0..31 chunk
    const int fo1 = (q * 8 + 32) ^ swz;     // k 32..63 chunk

    auto cell = [&]() {
        // ---- encoder (VALU fp32, both batches) ----
        float e[14];
        #pragma unroll
        for (int n = 0; n < 14; ++n) e[n] = benc;
        #pragma unroll
        for (int f = 0; f < 11; ++f) {
            float w = encwL[f * 64 + lane];
            #pragma unroll
            for (int n = 0; n < 7; ++n) {
                const int fl = n * 11 + f;
                float xa = (fl < 64) ? rdl(xr0, fl) : rdl(xr1, fl - 64);
                float xb = (fl < 64) ? rdl(xr2, fl) : rdl(xr3, fl - 64);
                e[n]     = fmaf(xa, w, e[n]);
                e[7 + n] = fmaf(xb, w, e[7 + n]);
            }
        }
        #pragma unroll
        for (int n = 0; n < 14; ++n) e[n] = fmaxf(e[n], 0.0f);
        // ---- mix1: ae = adj @ e ; split-store to Rs (swizzled) ----
        #pragma unroll
        for (int n = 0; n < 14; ++n) {
            const int rr = (n < 7) ? n : n + 1;
            float a = 0.f;
            #pragma unroll
            for (int m = 0; m < 7; ++m) {
                float am = (n < 7) ? rdl(adjr0, n * 7 + m) : rdl(adjr1, (n - 7) * 7 + m);
                a = fmaf(am, e[(n < 7 ? 0 : 7) + m], a);
            }
            unsigned short h, l; hsplit(a, h, l);
            const int cs = lane ^ ((rr & 7) << 3);
            aw[rr * 64 + cs] = h; aw[960 + rr * 64 + cs] = l;
        }
        WFENCE();
        // ---- gcn1 MFMA (weights from pinned registers) ----
        {
            s8v ah0 = *(const s8v*)(aw + c15 * 64 + fo0);
            s8v ah1 = *(const s8v*)(aw + c15 * 64 + fo1);
            s8v al0 = *(const s8v*)(aw + 960 + c15 * 64 + fo0);
            s8v al1 = *(const s8v*)(aw + 960 + c15 * 64 + fo1);
            ll64 a80 = pk8(ah0), a81 = pk8(ah1);
            f4v res[4];
            #pragma unroll
            for (int nt = 0; nt < 4; ++nt) {
                f4v A = {bg1v[nt], bg1v[nt], bg1v[nt], bg1v[nt]};
                f4v B = {0.f, 0.f, 0.f, 0.f};
                A = mfmah(ah0, chiR[nt * 2 + 0], A); A = mfmah(ah1, chiR[nt * 2 + 1], A);
                B = mfmah(al0, chiR[nt * 2 + 0], B); B = mfmah(al1, chiR[nt * 2 + 1], B);
                B = mfma8(a80, cloR[nt * 2 + 0], B); B = mfma8(a81, cloR[nt * 2 + 1], B);
                res[nt] = A + B * INV2048;
            }
            #pragma unroll
            for (int nt = 0; nt < 4; ++nt) {
                #pragma unroll
                for (int r = 0; r < 4; ++r) {
                    const int m = q * 4 + r;
                    float v = fmaxf(res[nt][r], 0.0f);
                    if ((m & 7) != 7) {
                        unsigned short h, l; hsplit(v, h, l);
                        const int cs = (nt * 16 + c15) ^ ((m & 7) << 3);
                        aw[m * 64 + cs] = h; aw[960 + m * 64 + cs] = l;
                    }
                }
            }
        }
        WFENCE();
        // ---- readback s1; mix2; store ae2 ----
        float s1[14];
        #pragma unroll
        for (int n = 0; n < 14; ++n) {
            const int rr = (n < 7) ? n : n + 1;
            const int cs = lane ^ ((rr & 7) << 3);
            s1[n] = hjoin(aw[rr * 64 + cs], aw[960 + rr * 64 + cs]);
        }
        #pragma unroll
        for (int n = 0; n < 14; ++n) {
            const int rr = (n < 7) ? n : n + 1;
            float a = 0.f;
            #pragma unroll
            for (int m = 0; m < 7; ++m) {
                float am = (n < 7) ? rdl(adjr0, n * 7 + m) : rdl(adjr1, (n - 7) * 7 + m);
                a = fmaf(am, s1[(n < 7 ? 0 : 7) + m], a);
            }
            unsigned short h, l; hsplit(a, h, l);
            const int cs = lane ^ ((rr & 7) << 3);
            aw[rr * 64 + cs] = h; aw[960 + rr * 64 + cs] = l;
        }
        WFENCE();
        // ---- gcn2 MFMA (weights from pinned registers) ----
        {
            s8v ah0 = *(const s8v*)(aw + c15 * 64 + fo0);
            s8v ah1 = *(const s8v*)(aw + c15 * 64 + fo1);
            s8v al0 = *(const s8v*)(aw + 960 + c15 * 64 + fo0);
            s8v al1 = *(const s8v*)(aw + 960 + c15 * 64 + fo1);
            ll64 a80 = pk8(ah0), a81 = pk8(ah1);
            f4v res[4];
            #pragma unroll
            for (int nt = 0; nt < 4; ++nt) {
                f4v A = {bg2v[nt], bg2v[nt], bg2v[nt], bg2v[nt]};
                f4v B = {0.f, 0.f, 0.f, 0.f};
                A = mfmah(ah0, chiR[8 + nt * 2 + 0], A); A = mfmah(ah1, chiR[8 + nt * 2 + 1], A);
                B = mfmah(al0, chiR[8 + nt * 2 + 0], B); B = mfmah(al1, chiR[8 + nt * 2 + 1], B);
                B = mfma8(a80, cloR[8 + nt * 2 + 0], B); B = mfma8(a81, cloR[8 + nt * 2 + 1], B);
                res[nt] = A + B * INV2048;
            }
            #pragma unroll
            for (int nt = 0; nt < 4; ++nt) {
                #pragma unroll
                for (int r = 0; r < 4; ++r) {
                    const int m = q * 4 + r;
                    float v = fmaxf(res[nt][r], 0.0f);
                    if ((m & 7) != 7) {
                        unsigned short h, l; hsplit(v, h, l);
                        const int cs = (nt * 16 + c15) ^ ((m & 7) << 3);
                        aw[m * 64 + cs] = h; aw[960 + m * 64 + cs] = l;
                    }
                }
            }
        }
        WFENCE();
        // ---- gates MFMA, hb-major, static indexing; GHI+GLO from LDS ----
        {
            s8v s2h0 = *(const s8v*)(aw + c15 * 64 + fo0);
            s8v s2h1 = *(const s8v*)(aw + c15 * 64 + fo1);
            s8v s2l0 = *(const s8v*)(aw + 960 + c15 * 64 + fo0);
            s8v s2l1 = *(const s8v*)(aw + 960 + c15 * 64 + fo1);
            s8v hxh0 = *(const s8v*)(aw + 1920 + c15 * 64 + fo0);
            s8v hxh1 = *(const s8v*)(aw + 1920 + c15 * 64 + fo1);
            s8v hxl0 = *(const s8v*)(aw + 2880 + c15 * 64 + fo0);
            s8v hxl1 = *(const s8v*)(aw + 2880 + c15 * 64 + fo1);
            ll64 s280 = pk8(s2h0), s281 = pk8(s2h1);
            ll64 hx80 = pk8(hxh0), hx81 = pk8(hxh1);
            #pragma unroll
            for (int hb = 0; hb < 4; ++hb) {
                f4v gv[4];
                #pragma unroll
                for (int gi = 0; gi < 4; ++gi) {
                    const int nt = gi * 4 + hb;       // gate gi, h-block hb
                    const int fb = nt * 4;
                    s8v wi0 = GHIv[(fb + 0) * 64 + lane];
                    s8v wi1 = GHIv[(fb + 1) * 64 + lane];
                    s8v wh0 = GHIv[(fb + 2) * 64 + lane];
                    s8v wh1 = GHIv[(fb + 3) * 64 + lane];
                    ll64 li0 = *(const ll64*)(GLO + (fb + 0) * 512 + lane * 8);
                    ll64 li1 = *(const ll64*)(GLO + (fb + 1) * 512 + lane * 8);
                    ll64 lh0 = *(const ll64*)(GLO + (fb + 2) * 512 + lane * 8);
                    ll64 lh1 = *(const ll64*)(GLO + (fb + 3) * 512 + lane * 8);
                    f4v A = {biasg[nt], biasg[nt], biasg[nt], biasg[nt]};
                    f4v B = {0.f, 0.f, 0.f, 0.f};
                    A = mfmah(s2h0, wi0, A); A = mfmah(s2h1, wi1, A);
                    A = mfmah(hxh0, wh0, A); A = mfmah(hxh1, wh1, A);
                    B = mfmah(s2l0, wi0, B); B = mfmah(s2l1, wi1, B);
                    B = mfmah(hxl0, wh0, B); B = mfmah(hxl1, wh1, B);
                    B = mfma8(s280, li0, B); B = mfma8(s281, li1, B);
                    B = mfma8(hx80, lh0, B); B = mfma8(hx81, lh1, B);
                    gv[gi] = A + B * INV2048;
                }
                // pointwise for columns hb*16+c15 (14 of 16 rows useful)
                #pragma unroll
                for (int r = 0; r < 4; ++r) {
                    float iv = fsigm(gv[0][r]);
                    float fv = fsigm(gv[1][r]);
                    float gg = ftanh_(gv[2][r]);
                    float ov = fsigm(gv[3][r]);
                    float cc = fmaf(fv, cx[hb * 4 + r], iv * gg);
                    cx[hb * 4 + r] = cc;
                    float hh = ov * ftanh_(cc);
                    const int m = q * 4 + r;
                    if ((m & 7) != 7) {
                        unsigned short h, l; hsplit(hh, h, l);
                        const int cs = (hb * 16 + c15) ^ ((m & 7) << 3);
                        aw[1920 + m * 64 + cs] = h;
                        aw[2880 + m * 64 + cs] = l;
                    }
                }
            }
        }
        WFENCE();
    };

    // ---- history scan (both batches) ----
    const float* xb0 = xh + (size_t)bat0 * 1848;
    const float* xb1 = xh + (size_t)bat1 * 1848;
    #pragma unroll 1
    for (int t = 0; t < 24; ++t) {
        xr0 = xb0[t * 77 + lane];
        xr1 = (lane < 13) ? xb0[t * 77 + 64 + lane] : 0.0f;
        xr2 = xb1[t * 77 + lane];
        xr3 = (lane < 13) ? xb1[t * 77 + 64 + lane] : 0.0f;
        cell();
    }
    // xr0..xr3 now hold x at t=23: static features persist there for all
    // future steps; dynamic lanes are updated in-register via ds_bpermute.

    // ---- dec1 weights: load + pin only now (first use is the future loop;
    //      shortens live-range overlap with the history scan) ----
    s8v dhiR[4];
    {
        const s8v* DHIg = (const s8v*)(ws + OFF_DHI);
        #pragma unroll
        for (int f = 0; f < 4; ++f) dhiR[f] = DHIg[f * 64 + lane];
        #pragma unroll
        for (int f = 0; f < 4; ++f) asm volatile("" : "+v"(dhiR[f]));
    }

    // ---- autoregressive future scan ----
    float* outb0 = out + (size_t)bat0 * 2016;
    float* outb1 = out + (size_t)bat1 * 2016;
    #pragma unroll 1
    for (int st = 0; st < 48; ++st) {
        cell();
        // dec1 MFMA (hi + act-lo cross): weights from pinned registers
        {
            s8v hxh0 = *(const s8v*)(aw + 1920 + c15 * 64 + fo0);
            s8v hxh1 = *(const s8v*)(aw + 1920 + c15 * 64 + fo1);
            s8v hxl0 = *(const s8v*)(aw + 2880 + c15 * 64 + fo0);
            s8v hxl1 = *(const s8v*)(aw + 2880 + c15 * 64 + fo1);
            #pragma unroll
            for (int nt = 0; nt < 2; ++nt) {
                f4v A = {bdec[nt], bdec[nt], bdec[nt], bdec[nt]};
                f4v B = {0.f, 0.f, 0.f, 0.f};
                A = mfmah(hxh0, dhiR[nt * 2 + 0], A); A = mfmah(hxh1, dhiR[nt * 2 + 1], A);
                B = mfmah(hxl0, dhiR[nt * 2 + 0], B); B = mfmah(hxl1, dhiR[nt * 2 + 1], B);
                f4v res = A + B * INV2048;
                #pragma unroll
                for (int r = 0; r < 4; ++r) {
                    const int m = q * 4 + r;
                    if ((m & 7) != 7) fw[m * 33 + nt * 16 + c15] = fmaxf(res[r], 0.0f);
                }
            }
        }
        WFENCE();
        // dec2 + residual + clip + store (both batches); pred stays in registers.
        // NOTE (R2 bug fix): ALL ds_bpermute calls must run at full EXEC.
        {
            float a0 = bd2, a1 = bd2;
            const float* fr0 = fw + dn * 33;
            const float* fr1 = fw + (dn + 8) * 33;
            #pragma unroll 8
            for (int jj = 0; jj < 32; ++jj) {
                float wv2 = d2wL[jj * 6 + dd];
                a0 = fmaf(fr0[jj], wv2, a0);
                a1 = fmaf(fr1[jj], wv2, a1);
            }
            float pa0 = bpermf(osA, xr0);
            float pb0 = bpermf(osB, xr1);
            float pa1 = bpermf(osA, xr2);
            float pb1 = bpermf(osB, xr3);
            float op0 = selA ? pa0 : pb0;
            float op1 = selA ? pa1 : pb1;
            float p0 = op0 + ftanh_(a0) * 0.05f;
            float p1 = op1 + ftanh_(a1) * 0.05f;
            p0 = fminf(fmaxf(p0, 0.0f), 1.0f);
            p1 = fminf(fmaxf(p1, 0.0f), 1.0f);
            if (lane < 42) {
                outb0[st * 42 + lane] = p0;
                outb1[st * 42 + lane] = p1;
            }
            // redistribute new preds back into xr registers (full-exec bpermutes)
            float n00 = bpermf(bs0, p0), n01 = bpermf(bs1, p0);
            float n10 = bpermf(bs0, p1), n11 = bpermf(bs1, p1);
            xr0 = up0 ? n00 : xr0;
            xr1 = up1 ? n01 : xr1;
            xr2 = up0 ? n10 : xr2;
            xr3 = up1 ? n11 : xr3;
        }
    }
}

extern "C" void kernel_launch(void* const* d_in, const int* in_sizes, int n_in,
                              void* d_out, int out_size, void* d_ws, size_t ws_size,
                              hipStream_t stream)
{
    const float* xh   = (const float*)d_in[0];
    const float* adjp = (const float*)d_in[1];
    const float* encw = (const float*)d_in[2];
    const float* encb = (const float*)d_in[3];
    const float* g1w  = (const float*)d_in[4];
    const float* g1b  = (const float*)d_in[5];
    const float* g2w  = (const float*)d_in[6];
    const float* g2b  = (const float*)d_in[7];
    const float* wih  = (const float*)d_in[8];
    const float* whh  = (const float*)d_in[9];
    const float* bih  = (const float*)d_in[10];
    const float* bhh  = (const float*)d_in[11];
    const float* d1w  = (const float*)d_in[12];
    const float* d1b  = (const float*)d_in[13];
    const float* d2w  = (const float*)d_in[14];
    const float* d2b  = (const float*)d_in[15];
    float* out = (float*)d_out;
    unsigned char* ws = (unsigned char*)d_ws;

    hipLaunchKernelGGL(build_ws, dim3(1), dim3(256), 0, stream, g1w, g2w, d1w, wih, whh, ws);
    hipLaunchKernelGGL(stgnn, dim3(256), dim3(512), 0, stream,
                       xh, adjp, encw, encb, g1b, g2b, bih, bhh,
                       d1b, d2w, d2b, (const unsigned char*)ws, out);
}

// Round 8
// 853.020 us; speedup vs baseline: 1.7878x; 1.7878x over previous
//
#include <hip/hip_runtime.h>
#include <math.h>

typedef __attribute__((ext_vector_type(8))) short s8v;
typedef __attribute__((ext_vector_type(8))) _Float16 h8v;
typedef __attribute__((ext_vector_type(4))) float f4v;
typedef __attribute__((ext_vector_type(2))) int i2v;
typedef long long ll64;

#define L2E 1.44269504089f
#define INV2048 4.8828125e-4f
__device__ __forceinline__ float fexp2(float x) { return __builtin_amdgcn_exp2f(x); }
__device__ __forceinline__ float frcp(float x)  { return __builtin_amdgcn_rcpf(x); }
__device__ __forceinline__ float fsigm(float x) { return frcp(1.0f + fexp2(-L2E * x)); }
__device__ __forceinline__ float ftanh_(float x){ return 1.0f - 2.0f * frcp(fexp2((2.0f*L2E) * x) + 1.0f); }
__device__ __forceinline__ float rdl(float v, int l) {
    return __uint_as_float(__builtin_amdgcn_readlane(__float_as_uint(v), l));
}
__device__ __forceinline__ float bpermf(int byteidx, float v) {
    return __uint_as_float(__builtin_amdgcn_ds_bpermute(byteidx, __float_as_uint(v)));
}
#define WFENCE() asm volatile("s_waitcnt lgkmcnt(0)" ::: "memory")

__device__ __forceinline__ unsigned short f2h(float x) {
    return __builtin_bit_cast(unsigned short, (_Float16)x);
}
__device__ __forceinline__ float h2f(unsigned short h) {
    return (float)__builtin_bit_cast(_Float16, h);
}
__device__ __forceinline__ f4v mfmah(s8v a, s8v b, f4v c) {
    return __builtin_amdgcn_mfma_f32_16x16x32_f16(
        __builtin_bit_cast(h8v, a), __builtin_bit_cast(h8v, b), c, 0, 0, 0);
}
__device__ __forceinline__ f4v mfma8(ll64 a, ll64 b, f4v c) {
    return __builtin_amdgcn_mfma_f32_16x16x32_fp8_fp8(a, b, c, 0, 0, 0);
}
// fp16x8 fragment -> fp8(e4m3)x8 operand (same k ordering: byte j = elem j)
__device__ __forceinline__ ll64 pk8(s8v hf) {
    h8v h = __builtin_bit_cast(h8v, hf);
    int lo = __builtin_amdgcn_cvt_pk_fp8_f32((float)h[0], (float)h[1], 0, false);
    lo = __builtin_amdgcn_cvt_pk_fp8_f32((float)h[2], (float)h[3], lo, true);
    int hi = __builtin_amdgcn_cvt_pk_fp8_f32((float)h[4], (float)h[5], 0, false);
    hi = __builtin_amdgcn_cvt_pk_fp8_f32((float)h[6], (float)h[7], hi, true);
    i2v r; r[0] = lo; r[1] = hi;
    return __builtin_bit_cast(ll64, r);
}
__device__ __forceinline__ unsigned char fp8b(float x) {
    return (unsigned char)(__builtin_amdgcn_cvt_pk_fp8_f32(x, 0.0f, 0, false) & 0xff);
}

// ---------------- d_ws layout (global, unchanged) ----------------
// GHI  [0,      65536): gates hi fp16, frag f = nt*4+mat*2+kh (64 frags x 1024 B)
// GLO  [65536,  98304): gates lo fp8  (64 frags x 512 B)
// CHI  [98304, 114688): gcn hi fp16,  frag f = g*8+nt*2+kh (16 x 1024)
// CLO  [114688,122880): gcn lo fp8    (16 x 512)
// DHI  [122880,126976): dec hi fp16,  frag f = nt*2+kh (4 x 1024)
#define OFF_GLO  65536
#define OFF_CHI  98304
#define OFF_CLO  114688
#define OFF_DHI  122880

// ---------------- LDS layout (bytes), total 159232 ----------------
// ALL weights LDS-resident (R0-proven: no fetch storm, VGPR<=128 is enough):
// GHI  [0,      65536)
// GLO  [65536,  98304)
// CHI  [98304, 114688)
// CLO  [114688,122880)
// DHI  [122880,126976)
// ACTS [126976,155648): 8 waves x 3584 B (1792 shorts):
//   SHI shorts [0,896)   = 14 rows x 64, fp16 HI ONLY (act-lo dropped)
//   HHI shorts [896,1792) = 14 rows x 64, fp16 HI ONLY
//   14-row packing: batch0 -> rows 0-6, batch1 -> rows 7-13 (mask m<14).
//   XOR swizzle: col' = col ^ ((row&7)<<3).
//   (c15=14/15 fragment reads overflow into following region: garbage, masked.)
// ENCW [155648,158464): enc_w fp32 (704 floats)
// D2W  [158464,159232): dec_w2 fp32 (192 floats)
#define L_CHI   98304
#define L_CLO   114688
#define L_DHI   122880
#define L_ACT   126976
#define L_ENCW  155648
#define L_D2W   158464

// ---------- prologue: build ALL weight fragments into d_ws (unchanged) ----------
__global__ __launch_bounds__(256) void build_ws(
    const float* __restrict__ g1w, const float* __restrict__ g2w,
    const float* __restrict__ d1w, const float* __restrict__ wih,
    const float* __restrict__ whh, unsigned char* __restrict__ ws)
{
    const int tid = threadIdx.x;  // 256
    unsigned short* GHI = (unsigned short*)ws;
    unsigned char*  GLO = ws + OFF_GLO;
    unsigned short* CHI = (unsigned short*)(ws + OFF_CHI);
    unsigned char*  CLO = ws + OFF_CLO;
    unsigned short* DHI = (unsigned short*)(ws + OFF_DHI);

    // gates: B[k][c] = wih/whh[c*64+k]
    for (int u = tid; u < 4096; u += 256) {
        int f = u >> 6, ln = u & 63;
        int nt = f >> 2, mat = (f >> 1) & 1, kh = f & 1;
        int col = nt * 16 + (ln & 15);
        int k0 = kh * 32 + ((ln >> 4) & 3) * 8;
        const float* W = mat ? whh : wih;
        #pragma unroll
        for (int j = 0; j < 8; ++j) {
            float w = W[col * 64 + k0 + j];
            _Float16 h = (_Float16)w;
            float r = (w - (float)h) * 2048.0f;
            GHI[f * 512 + ln * 8 + j] = __builtin_bit_cast(unsigned short, h);
            GLO[f * 512 + ln * 8 + j] = fp8b(r);
        }
    }
    // gcn: B[k][n] = W[k*64+n]
    for (int u = tid; u < 1024; u += 256) {
        int f = u >> 6, ln = u & 63;
        int g = f >> 3, nt = (f >> 1) & 3, kh = f & 1;
        int n = nt * 16 + (ln & 15);
        int k0 = kh * 32 + ((ln >> 4) & 3) * 8;
        const float* W = g ? g2w : g1w;
        #pragma unroll
        for (int j = 0; j < 8; ++j) {
            float w = W[(k0 + j) * 64 + n];
            _Float16 h = (_Float16)w;
            float r = (w - (float)h) * 2048.0f;
            CHI[f * 512 + ln * 8 + j] = __builtin_bit_cast(unsigned short, h);
            CLO[f * 512 + ln * 8 + j] = fp8b(r);
        }
    }
    // dec: B[k][j] = d1w[k*32+j], hi only
    for (int u = tid; u < 256; u += 256) {
        int f = u >> 6, ln = u & 63;
        int nt = f >> 1, kh = f & 1;
        int n = nt * 16 + (ln & 15);
        int k0 = kh * 32 + ((ln >> 4) & 3) * 8;
        #pragma unroll
        for (int j = 0; j < 8; ++j) {
            _Float16 h = (_Float16)d1w[(k0 + j) * 32 + n];
            DHI[f * 512 + ln * 8 + j] = __builtin_bit_cast(unsigned short, h);
        }
    }
}

// ---------- main kernel: one wave = TWO batches (rows 0-6 / 7-13), one pass ----------
// R8 structure: ALL weights in LDS (the R0-proven residency; no pinned-register
// path, no spill storm possible). Budget closed by hi-only fp16 acts (weight-lo
// corrections GLO/CLO kept: weight rounding is a fixed bias that accumulates
// linearly over 72 steps; act rounding is quasi-random, ~1e-3 sqrt-accumulated)
// and 14-row act packing (batch1 at rows 7-13, mask m<14).
__global__ __launch_bounds__(512, 2)
void stgnn(const float* __restrict__ xh,   const float* __restrict__ adj,
           const float* __restrict__ encw, const float* __restrict__ encb,
           const float* __restrict__ g1b,  const float* __restrict__ g2b,
           const float* __restrict__ bih,  const float* __restrict__ bhh,
           const float* __restrict__ d1b,  const float* __restrict__ d2w,
           const float* __restrict__ d2b,  const unsigned char* __restrict__ ws,
           float* __restrict__ out)
{
    __shared__ __align__(16) unsigned char pool[159232];

    const int tid  = threadIdx.x;
    const int lane = tid & 63;
    const int wv   = tid >> 6;
    const int q    = lane >> 4;
    const int c15  = lane & 15;
    const int bat0 = blockIdx.x * 16 + wv * 2;
    const int bat1 = bat0 + 1;

    // ---- one-time: stage ALL weights (contiguous 126976 B) + encw/d2w ----
    {
        s8v* dst = (s8v*)pool;
        const s8v* src = (const s8v*)ws;
        for (int i = tid; i < 7936; i += 512) dst[i] = src[i];
        float* pe = (float*)(pool + L_ENCW);
        for (int i = tid; i < 704; i += 512) pe[i] = encw[i];
        float* pd = (float*)(pool + L_D2W);
        if (tid < 192) pd[tid] = d2w[tid];
    }

    unsigned short* aw = (unsigned short*)(pool + L_ACT) + wv * 1792;
    float* fw = (float*)aw;                       // float view of own act region
    const s8v* GHIv = (const s8v*)pool;
    const unsigned char* GLO = pool + OFF_GLO;
    const s8v* CHIv = (const s8v*)(pool + L_CHI);
    const unsigned char* CLO = pool + L_CLO;
    const s8v* DHIv = (const s8v*)(pool + L_DHI);
    const float* encwL = (const float*)(pool + L_ENCW);
    const float* d2wL  = (const float*)(pool + L_D2W);

    // ---- biases ----
    float benc = encb[lane];
    float bg1v[4], bg2v[4], bdec[2], biasg[16];
    #pragma unroll
    for (int i = 0; i < 4; ++i) { bg1v[i] = g1b[i * 16 + c15]; bg2v[i] = g2b[i * 16 + c15]; }
    #pragma unroll
    for (int i = 0; i < 2; ++i) bdec[i] = d1b[i * 16 + c15];
    #pragma unroll
    for (int i = 0; i < 16; ++i) biasg[i] = bih[i * 16 + c15] + bhh[i * 16 + c15];
    const int dn = lane / 6, dd = lane - dn * 6;    // dec2 mapping (lane<42)
    float bd2 = d2b[lane < 42 ? dd : 0];
    // lane-permutation constants for in-register pred redistribution
    const int l11  = lane - (lane / 11) * 11;       // lane % 11
    const bool up0 = (l11 < 6);                     // dynamic lanes in xr0
    const bool up1 = (lane >= 2) && (lane < 8);     // dynamic lanes in xr1
    const int fsrc = dn * 11 + dd;                  // old-pred source flat index
    const int osA  = fsrc * 4;                      // pull from xr0
    const int osB  = (fsrc >= 64 ? (fsrc - 64) : 0) * 4;  // pull from xr1 (dn==6)
    const bool selA = (dn < 6);
    const int bs0  = ((lane / 11) * 6 + l11) * 4;   // new-pred source for xr0 lanes
    const int bs1  = (34 + lane) * 4;               // new-pred source for xr1 lanes

    // ---- adjacency normalize for BOTH batches (wave-local float scratch) ----
    if (lane < 49) {
        int ai = lane / 7, aj = lane - ai * 7;
        float a0 = adj[(size_t)bat0 * 49 + lane];
        float a1 = adj[(size_t)bat1 * 49 + lane];
        if (ai == aj) { a0 = 1.0f; a1 = 1.0f; }
        fw[lane] = a0; fw[56 + lane] = a1;
    }
    WFENCE();
    float adjr0 = 0.0f, adjr1 = 0.0f;
    if (lane < 49) {
        int ai = lane / 7, aj = lane - ai * 7;
        float si0 = 0.f, sj0 = 0.f, si1 = 0.f, sj1 = 0.f;
        #pragma unroll
        for (int m = 0; m < 7; ++m) {
            si0 += fw[ai * 7 + m]; sj0 += fw[aj * 7 + m];
            si1 += fw[56 + ai * 7 + m]; sj1 += fw[56 + aj * 7 + m];
        }
        si0 = fmaxf(si0, 1.0f); sj0 = fmaxf(sj0, 1.0f);
        si1 = fmaxf(si1, 1.0f); sj1 = fmaxf(sj1, 1.0f);
        adjr0 = fw[lane] / (sqrtf(si0) * sqrtf(sj0));
        adjr1 = fw[56 + lane] / (sqrtf(si1) * sqrtf(sj1));
    }
    WFENCE();
    // zero hx (HHI rows 0-13)
    #pragma unroll
    for (int i = 0; i < 14; ++i) aw[896 + i * 64 + lane] = 0;
    WFENCE();
    __syncthreads();   // LDS staging complete

    float cx[16];
    #pragma unroll
    for (int i = 0; i < 16; ++i) cx[i] = 0.0f;
    float xr0 = 0.f, xr1 = 0.f, xr2 = 0.f, xr3 = 0.f;

    // swizzled fragment k-offsets (within-row): col' = col ^ ((row&7)<<3)
    const int swz = (c15 & 7) << 3;
    const int fo0 = (q * 8) ^ swz;          // k 0..31 chunk
    const int fo1 = (q * 8 + 32) ^ swz;     // k 32..63 chunk

    auto cell = [&]() {
        // ---- encoder (VALU fp32, both batches) ----
        float e[14];
        #pragma unroll
        for (int n = 0; n < 14; ++n) e[n] = benc;
        #pragma unroll
        for (int f = 0; f < 11; ++f) {
            float w = encwL[f * 64 + lane];
            #pragma unroll
            for (int n = 0; n < 7; ++n) {
                const int fl = n * 11 + f;
                float xa = (fl < 64) ? rdl(xr0, fl) : rdl(xr1, fl - 64);
                float xb = (fl < 64) ? rdl(xr2, fl) : rdl(xr3, fl - 64);
                e[n]     = fmaf(xa, w, e[n]);
                e[7 + n] = fmaf(xb, w, e[7 + n]);
            }
        }
        #pragma unroll
        for (int n = 0; n < 14; ++n) e[n] = fmaxf(e[n], 0.0f);
        // ---- mix1: ae = adj @ e ; fp16 store to S (rows n 0..13, swizzled) ----
        #pragma unroll
        for (int n = 0; n < 14; ++n) {
            float a = 0.f;
            #pragma unroll
            for (int m = 0; m < 7; ++m) {
                float am = (n < 7) ? rdl(adjr0, n * 7 + m) : rdl(adjr1, (n - 7) * 7 + m);
                a = fmaf(am, e[(n < 7 ? 0 : 7) + m], a);
            }
            aw[n * 64 + (lane ^ ((n & 7) << 3))] = f2h(a);
        }
        WFENCE();
        // ---- gcn1 MFMA (hi acts; weight-lo correction via act-hi fp8) ----
        {
            s8v ah0 = *(const s8v*)(aw + c15 * 64 + fo0);
            s8v ah1 = *(const s8v*)(aw + c15 * 64 + fo1);
            ll64 a80 = pk8(ah0), a81 = pk8(ah1);
            f4v res[4];
            #pragma unroll
            for (int nt = 0; nt < 4; ++nt) {
                s8v wh0 = CHIv[(nt * 2 + 0) * 64 + lane];
                s8v wh1 = CHIv[(nt * 2 + 1) * 64 + lane];
                ll64 wl0 = *(const ll64*)(CLO + (nt * 2 + 0) * 512 + lane * 8);
                ll64 wl1 = *(const ll64*)(CLO + (nt * 2 + 1) * 512 + lane * 8);
                f4v A = {bg1v[nt], bg1v[nt], bg1v[nt], bg1v[nt]};
                f4v B = {0.f, 0.f, 0.f, 0.f};
                A = mfmah(ah0, wh0, A); A = mfmah(ah1, wh1, A);
                B = mfma8(a80, wl0, B); B = mfma8(a81, wl1, B);
                res[nt] = A + B * INV2048;
            }
            #pragma unroll
            for (int nt = 0; nt < 4; ++nt) {
                #pragma unroll
                for (int r = 0; r < 4; ++r) {
                    const int m = q * 4 + r;
                    if (m < 14)
                        aw[m * 64 + ((nt * 16 + c15) ^ ((m & 7) << 3))] =
                            f2h(fmaxf(res[nt][r], 0.0f));
                }
            }
        }
        WFENCE();
        // ---- readback s1; mix2; store ae2 ----
        float s1[14];
        #pragma unroll
        for (int n = 0; n < 14; ++n)
            s1[n] = h2f(aw[n * 64 + (lane ^ ((n & 7) << 3))]);
        #pragma unroll
        for (int n = 0; n < 14; ++n) {
            float a = 0.f;
            #pragma unroll
            for (int m = 0; m < 7; ++m) {
                float am = (n < 7) ? rdl(adjr0, n * 7 + m) : rdl(adjr1, (n - 7) * 7 + m);
                a = fmaf(am, s1[(n < 7 ? 0 : 7) + m], a);
            }
            aw[n * 64 + (lane ^ ((n & 7) << 3))] = f2h(a);
        }
        WFENCE();
        // ---- gcn2 MFMA ----
        {
            s8v ah0 = *(const s8v*)(aw + c15 * 64 + fo0);
            s8v ah1 = *(const s8v*)(aw + c15 * 64 + fo1);
            ll64 a80 = pk8(ah0), a81 = pk8(ah1);
            f4v res[4];
            #pragma unroll
            for (int nt = 0; nt < 4; ++nt) {
                s8v wh0 = CHIv[(8 + nt * 2 + 0) * 64 + lane];
                s8v wh1 = CHIv[(8 + nt * 2 + 1) * 64 + lane];
                ll64 wl0 = *(const ll64*)(CLO + (8 + nt * 2 + 0) * 512 + lane * 8);
                ll64 wl1 = *(const ll64*)(CLO + (8 + nt * 2 + 1) * 512 + lane * 8);
                f4v A = {bg2v[nt], bg2v[nt], bg2v[nt], bg2v[nt]};
                f4v B = {0.f, 0.f, 0.f, 0.f};
                A = mfmah(ah0, wh0, A); A = mfmah(ah1, wh1, A);
                B = mfma8(a80, wl0, B); B = mfma8(a81, wl1, B);
                res[nt] = A + B * INV2048;
            }
            #pragma unroll
            for (int nt = 0; nt < 4; ++nt) {
                #pragma unroll
                for (int r = 0; r < 4; ++r) {
                    const int m = q * 4 + r;
                    if (m < 14)
                        aw[m * 64 + ((nt * 16 + c15) ^ ((m & 7) << 3))] =
                            f2h(fmaxf(res[nt][r], 0.0f));
                }
            }
        }
        WFENCE();
        // ---- gates MFMA, hb-major, static indexing; all weights from LDS ----
        {
            s8v s2h0 = *(const s8v*)(aw + c15 * 64 + fo0);
            s8v s2h1 = *(const s8v*)(aw + c15 * 64 + fo1);
            s8v hxh0 = *(const s8v*)(aw + 896 + c15 * 64 + fo0);
            s8v hxh1 = *(const s8v*)(aw + 896 + c15 * 64 + fo1);
            ll64 s280 = pk8(s2h0), s281 = pk8(s2h1);
            ll64 hx80 = pk8(hxh0), hx81 = pk8(hxh1);
            #pragma unroll
            for (int hb = 0; hb < 4; ++hb) {
                f4v gv[4];
                #pragma unroll
                for (int gi = 0; gi < 4; ++gi) {
                    const int nt = gi * 4 + hb;       // gate gi, h-block hb
                    const int fb = nt * 4;
                    s8v wi0 = GHIv[(fb + 0) * 64 + lane];
                    s8v wi1 = GHIv[(fb + 1) * 64 + lane];
                    s8v wh0 = GHIv[(fb + 2) * 64 + lane];
                    s8v wh1 = GHIv[(fb + 3) * 64 + lane];
                    ll64 li0 = *(const ll64*)(GLO + (fb + 0) * 512 + lane * 8);
                    ll64 li1 = *(const ll64*)(GLO + (fb + 1) * 512 + lane * 8);
                    ll64 lh0 = *(const ll64*)(GLO + (fb + 2) * 512 + lane * 8);
                    ll64 lh1 = *(const ll64*)(GLO + (fb + 3) * 512 + lane * 8);
                    f4v A = {biasg[nt], biasg[nt], biasg[nt], biasg[nt]};
                    f4v B = {0.f, 0.f, 0.f, 0.f};
                    A = mfmah(s2h0, wi0, A); A = mfmah(s2h1, wi1, A);
                    A = mfmah(hxh0, wh0, A); A = mfmah(hxh1, wh1, A);
                    B = mfma8(s280, li0, B); B = mfma8(s281, li1, B);
                    B = mfma8(hx80, lh0, B); B = mfma8(hx81, lh1, B);
                    gv[gi] = A + B * INV2048;
                }
                // pointwise for columns hb*16+c15 (rows m<14 valid)
                #pragma unroll
                for (int r = 0; r < 4; ++r) {
                    float iv = fsigm(gv[0][r]);
                    float fv = fsigm(gv[1][r]);
                    float gg = ftanh_(gv[2][r]);
                    float ov = fsigm(gv[3][r]);
                    float cc = fmaf(fv, cx[hb * 4 + r], iv * gg);
                    cx[hb * 4 + r] = cc;
                    float hh = ov * ftanh_(cc);
                    const int m = q * 4 + r;
                    if (m < 14)
                        aw[896 + m * 64 + ((hb * 16 + c15) ^ ((m & 7) << 3))] = f2h(hh);
                }
            }
        }
        WFENCE();
    };

    // ---- history scan (both batches) ----
    const float* xb0 = xh + (size_t)bat0 * 1848;
    const float* xb1 = xh + (size_t)bat1 * 1848;
    #pragma unroll 1
    for (int t = 0; t < 24; ++t) {
        xr0 = xb0[t * 77 + lane];
        xr1 = (lane < 13) ? xb0[t * 77 + 64 + lane] : 0.0f;
        xr2 = xb1[t * 77 + lane];
        xr3 = (lane < 13) ? xb1[t * 77 + 64 + lane] : 0.0f;
        cell();
    }
    // xr0..xr3 hold x at t=23; static features persist there, dynamic lanes
    // updated in-register via ds_bpermute each future step.

    // ---- autoregressive future scan ----
    float* outb0 = out + (size_t)bat0 * 2016;
    float* outb1 = out + (size_t)bat1 * 2016;
    #pragma unroll 1
    for (int st = 0; st < 48; ++st) {
        cell();
        // dec1 MFMA (hi only); output as fp16 stride-33 shorts in dead S region
        {
            s8v hxh0 = *(const s8v*)(aw + 896 + c15 * 64 + fo0);
            s8v hxh1 = *(const s8v*)(aw + 896 + c15 * 64 + fo1);
            #pragma unroll
            for (int nt = 0; nt < 2; ++nt) {
                s8v wh0 = DHIv[(nt * 2 + 0) * 64 + lane];
                s8v wh1 = DHIv[(nt * 2 + 1) * 64 + lane];
                f4v A = {bdec[nt], bdec[nt], bdec[nt], bdec[nt]};
                A = mfmah(hxh0, wh0, A); A = mfmah(hxh1, wh1, A);
                #pragma unroll
                for (int r = 0; r < 4; ++r) {
                    const int m = q * 4 + r;
                    if (m < 14) aw[m * 33 + nt * 16 + c15] = f2h(fmaxf(A[r], 0.0f));
                }
            }
        }
        WFENCE();
        // dec2 + residual + clip + store (both batches); pred stays in registers.
        // NOTE (R2 bug fix): ALL ds_bpermute calls must run at full EXEC.
        {
            float a0 = bd2, a1 = bd2;
            #pragma unroll 8
            for (int jj = 0; jj < 32; ++jj) {
                float wv2 = d2wL[jj * 6 + dd];
                a0 = fmaf(h2f(aw[dn * 33 + jj]), wv2, a0);
                a1 = fmaf(h2f(aw[(7 + dn) * 33 + jj]), wv2, a1);
            }
            float pa0 = bpermf(osA, xr0);
            float pb0 = bpermf(osB, xr1);
            float pa1 = bpermf(osA, xr2);
            float pb1 = bpermf(osB, xr3);
            float op0 = selA ? pa0 : pb0;
            float op1 = selA ? pa1 : pb1;
            float p0 = op0 + ftanh_(a0) * 0.05f;
            float p1 = op1 + ftanh_(a1) * 0.05f;
            p0 = fminf(fmaxf(p0, 0.0f), 1.0f);
            p1 = fminf(fmaxf(p1, 0.0f), 1.0f);
            if (lane < 42) {
                outb0[st * 42 + lane] = p0;
                outb1[st * 42 + lane] = p1;
            }
            // redistribute new preds back into xr registers (full-exec bpermutes)
            float n00 = bpermf(bs0, p0), n01 = bpermf(bs1, p0);
            float n10 = bpermf(bs0, p1), n11 = bpermf(bs1, p1);
            xr0 = up0 ? n00 : xr0;
            xr1 = up1 ? n01 : xr1;
            xr2 = up0 ? n10 : xr2;
            xr3 = up1 ? n11 : xr3;
        }
    }
}

extern "C" void kernel_launch(void* const* d_in, const int* in_sizes, int n_in,
                              void* d_out, int out_size, void* d_ws, size_t ws_size,
                              hipStream_t stream)
{
    const float* xh   = (const float*)d_in[0];
    const float* adjp = (const float*)d_in[1];
    const float* encw = (const float*)d_in[2];
    const float* encb = (const float*)d_in[3];
    const float* g1w  = (const float*)d_in[4];
    const float* g1b  = (const float*)d_in[5];
    const float* g2w  = (const float*)d_in[6];
    const float* g2b  = (const float*)d_in[7];
    const float* wih  = (const float*)d_in[8];
    const float* whh  = (const float*)d_in[9];
    const float* bih  = (const float*)d_in[10];
    const float* bhh  = (const float*)d_in[11];
    const float* d1w  = (const float*)d_in[12];
    const float* d1b  = (const float*)d_in[13];
    const float* d2w  = (const float*)d_in[14];
    const float* d2b  = (const float*)d_in[15];
    float* out = (float*)d_out;
    unsigned char* ws = (unsigned char*)d_ws;

    hipLaunchKernelGGL(build_ws, dim3(1), dim3(256), 0, stream, g1w, g2w, d1w, wih, whh, ws);
    hipLaunchKernelGGL(stgnn, dim3(256), dim3(512), 0, stream,
                       xh, adjp, encw, encb, g1b, g2b, bih, bhh,
                       d1b, d2w, d2b, (const unsigned char*)ws, out);
}